// Round 4
// baseline (472.436 us; speedup 1.0000x reference)
//
#include <hip/hip_runtime.h>
#include <hip/hip_fp16.h>
#include <stdint.h>

#define NB 256     // batch
#define NI 1152    // input capsules
#define DI 8       // input capsule dim
#define NO 10      // output capsules
#define NK 16      // output capsule dim
#define NC 36      // i-chunks of 32
#define XPAD 9

// ws layout (u32 units):
//   u_hat fp16: [b][c36][h2][o10][il32][k8 as 4xu32] = 23,592,960 u32 (90 MiB)
//   part fp32:  [c36][b][o][k16] = 1,474,560 f32 (5.6 MiB)   (0.1 * 32-i partial sums)
#define PART_OFF_U32 23592960u
#define WS_NEED ((23592960ull + 1474560ull) * 4ull)

// ---------------------------------------------------------------------------
// Kernel A: u_hat -> fp16 planes (coalesced) + non-atomic s0 partials
// grid (36, 16), 320 thr = (o10, il32)
// ---------------------------------------------------------------------------
__global__ __launch_bounds__(320)
void uhat_kernel(const float* __restrict__ x, const float* __restrict__ W,
                 uint32_t* __restrict__ ws)
{
    __shared__ float x_lds[16 * 32 * XPAD];   // [bb][il][d], 18.4 KB

    const int c   = blockIdx.x;
    const int b0  = blockIdx.y * 16;
    const int tid = threadIdx.x;
    const int o   = tid >> 5;
    const int il  = tid & 31;

    for (int idx = tid; idx < 16 * 256; idx += 320) {
        const int bb = idx >> 8, r = idx & 255;
        x_lds[bb * (32 * XPAD) + (r >> 3) * XPAD + (r & 7)] =
            x[(size_t)(b0 + bb) * (NI * DI) + c * 256 + r];
    }
    __syncthreads();

    const int i = c * 32 + il;
    const float4* wp = reinterpret_cast<const float4*>(W + ((size_t)i * NO + o) * (NK * DI));
    float* part = reinterpret_cast<float*>(ws + PART_OFF_U32);

#pragma unroll
    for (int h = 0; h < 2; ++h) {          // k = h*8 + kk
        float4 wr[16];
#pragma unroll
        for (int t = 0; t < 16; ++t) wr[t] = wp[h * 16 + t];

        for (int bb = 0; bb < 16; ++bb) {
            const int b = b0 + bb;
            float xr[DI];
#pragma unroll
            for (int d = 0; d < DI; ++d) xr[d] = x_lds[bb * (32 * XPAD) + il * XPAD + d];

            float u[8];
#pragma unroll
            for (int kk = 0; kk < 8; ++kk) {
                const float4 w0 = wr[2 * kk], w1 = wr[2 * kk + 1];
                u[kk] = w0.x * xr[0] + w0.y * xr[1] + w0.z * xr[2] + w0.w * xr[3] +
                        w1.x * xr[4] + w1.y * xr[5] + w1.z * xr[6] + w1.w * xr[7];
            }

            uint32_t pk[4];
#pragma unroll
            for (int t = 0; t < 4; ++t) {
                union { __half2 h2; uint32_t w; } cv;
                cv.h2 = __float22half2_rn(make_float2(u[2 * t], u[2 * t + 1]));
                pk[t] = cv.w;
            }
            // coalesced: wave (2 o's x 32 il) writes 1024B dense
            const size_t base = ((((size_t)b * NC + c) * 2 + h) * NO + o) * 128 + il * 4;
            *reinterpret_cast<uint4*>(ws + base) = make_uint4(pk[0], pk[1], pk[2], pk[3]);

            // il-reduce (masks <=16 stay within each 32-lane o-half)
            float r8[8];
#pragma unroll
            for (int kk = 0; kk < 8; ++kk) r8[kk] = u[kk];
#pragma unroll
            for (int m = 16; m >= 1; m >>= 1)
#pragma unroll
                for (int kk = 0; kk < 8; ++kk) r8[kk] += __shfl_xor(r8[kk], m, 64);
            if (il == 0) {
                float* pp = part + (((size_t)c * NB + b) * NO + o) * NK + h * 8;
                *reinterpret_cast<float4*>(pp) =
                    make_float4(0.1f * r8[0], 0.1f * r8[1], 0.1f * r8[2], 0.1f * r8[3]);
                *(reinterpret_cast<float4*>(pp) + 1) =
                    make_float4(0.1f * r8[4], 0.1f * r8[5], 0.1f * r8[6], 0.1f * r8[7]);
            }
        }
    }
}

// ---------------------------------------------------------------------------
// Kernel B: routing. grid 256 (block per b), 1024 thr = 16 waves.
// lane l: op = l/6 (output capsule), ii = l%6 (i-sub); 60 active lanes.
// Wave w owns i in [w*72, (w+1)*72) as 12 rounds of 6.
// ---------------------------------------------------------------------------
__global__ __launch_bounds__(1024)
void route_kernel(const float* __restrict__ bias, float* __restrict__ out,
                  const uint32_t* __restrict__ ws)
{
    __shared__ float v_lds[NO * NK];
    __shared__ float s_red[16][NO * NK];

    const int tid = threadIdx.x;
    const int b   = blockIdx.x;
    const int w   = tid >> 6;
    const int l   = tid & 63;
    int op = l / 6, ii = l - op * 6;
    const bool active = (l < 60);
    if (!active) { op = 0; ii = 0; }

    // hoisted shuffle source lanes (round/iter-invariant)
    int src_sm[9], src_rd[5];
#pragma unroll
    for (int j = 1; j <= 9; ++j) {
        int oo = op + j; if (oo >= NO) oo -= NO;
        src_sm[j - 1] = oo * 6 + ii;
    }
#pragma unroll
    for (int j = 1; j <= 5; ++j) {
        int t = ii + j; if (t >= 6) t -= 6;
        src_rd[j - 1] = op * 6 + t;
    }

    // ---- prologue: v0 = squash(sum_c part + bias) ----
    const float* part = reinterpret_cast<const float*>(ws + PART_OFF_U32);
    if (tid < NO * NK) {
        float sv = bias[tid];
#pragma unroll 6
        for (int cc = 0; cc < NC; ++cc) sv += part[((size_t)cc * NB + b) * (NO * NK) + tid];
        float sq = sv * sv;
#pragma unroll
        for (int m = 8; m >= 1; m >>= 1) sq += __shfl_xor(sq, m, 64);
        const float scale = sq / (1.f + sq) / sqrtf(sq + 1e-9f);
        v_lds[tid] = scale * sv;
    }
    __syncthreads();

    const uint32_t* ub = ws + (size_t)b * 92160;   // [c][h][o][il][4]
    float blog[12];

    // per-round u32 offset: c*2560 + h*1280 + op*128 + il*4
    auto off0 = [&](int r) -> int {
        const int i = w * 72 + r * 6 + ii;
        return (i >> 5) * 2560 + op * 128 + (i & 31) * 4;
    };

    for (int it = 0; it < 2; ++it) {
        float v[NK];
#pragma unroll
        for (int k = 0; k < NK; ++k) v[k] = v_lds[op * NK + k];

        float s_acc[NK];
#pragma unroll
        for (int k = 0; k < NK; ++k) s_acc[k] = 0.f;

        // 2-deep prefetch
        uint4 pa0 = *reinterpret_cast<const uint4*>(ub + off0(0));
        uint4 pa1 = *reinterpret_cast<const uint4*>(ub + off0(0) + 1280);
        uint4 pb0 = *reinterpret_cast<const uint4*>(ub + off0(1));
        uint4 pb1 = *reinterpret_cast<const uint4*>(ub + off0(1) + 1280);

#pragma unroll
        for (int r = 0; r < 12; ++r) {
            const uint4 q0 = (r & 1) ? pb0 : pa0;
            const uint4 q1 = (r & 1) ? pb1 : pa1;
            if (r + 2 < 12) {
                const int of = off0(r + 2);
                if (r & 1) { pb0 = *reinterpret_cast<const uint4*>(ub + of);
                             pb1 = *reinterpret_cast<const uint4*>(ub + of + 1280); }
                else       { pa0 = *reinterpret_cast<const uint4*>(ub + of);
                             pa1 = *reinterpret_cast<const uint4*>(ub + of + 1280); }
            }

            float f[NK];
            {
                const uint32_t qq[8] = {q0.x, q0.y, q0.z, q0.w, q1.x, q1.y, q1.z, q1.w};
#pragma unroll
                for (int t = 0; t < 8; ++t) {
                    union { uint32_t u; __half2 h2; } cv; cv.u = qq[t];
                    const float2 g = __half22float2(cv.h2);
                    f[2 * t] = g.x; f[2 * t + 1] = g.y;
                }
            }

            float a = 0.f;
#pragma unroll
            for (int k = 0; k < NK; ++k) a += f[k] * v[k];

            const float tot = (it == 0) ? a : (blog[r] + a);
            blog[r] = tot;

            const float e = __expf(tot);
            float den = e;
#pragma unroll
            for (int j = 0; j < 9; ++j) den += __shfl(e, src_sm[j], 64);
            const float cfac = e / den;

#pragma unroll
            for (int k = 0; k < NK; ++k) s_acc[k] += cfac * f[k];
        }

        // reduce s over the 6 ii-lanes (rotation sum of the frozen s_acc)
        float s_tot[NK];
#pragma unroll
        for (int k = 0; k < NK; ++k) s_tot[k] = s_acc[k];
#pragma unroll
        for (int j = 0; j < 5; ++j)
#pragma unroll
            for (int k = 0; k < NK; ++k) s_tot[k] += __shfl(s_acc[k], src_rd[j], 64);

        if (active && ii == 0) {
#pragma unroll
            for (int k = 0; k < NK; ++k) s_red[w][op * NK + k] = s_tot[k];
        }
        __syncthreads();

        if (tid < NO * NK) {
            float sv = bias[tid];
#pragma unroll
            for (int ww = 0; ww < 16; ++ww) sv += s_red[ww][tid];
            float sq = sv * sv;
#pragma unroll
            for (int m = 8; m >= 1; m >>= 1) sq += __shfl_xor(sq, m, 64);
            const float scale = sq / (1.f + sq) / sqrtf(sq + 1e-9f);
            if (it == 1) out[(size_t)b * (NO * NK) + tid] = scale * sv;
            else         v_lds[tid] = scale * sv;
        }
        __syncthreads();
    }
}

// ---------------------------------------------------------------------------
// Fallback (ws too small): monolithic, recompute u_hat per pass
// ---------------------------------------------------------------------------
__device__ __forceinline__ void compute_uhat_fb(int i, int o,
        const float* x_lds, const float* __restrict__ W, float* u)
{
    float xr[DI];
#pragma unroll
    for (int d = 0; d < DI; ++d) xr[d] = x_lds[i * XPAD + d];
    const float4* wp = reinterpret_cast<const float4*>(W + (size_t)(i * NO + o) * (NK * DI));
#pragma unroll
    for (int k = 0; k < NK; ++k) {
        float4 w0 = wp[2 * k], w1 = wp[2 * k + 1];
        u[k] = w0.x * xr[0] + w0.y * xr[1] + w0.z * xr[2] + w0.w * xr[3] +
               w1.x * xr[4] + w1.y * xr[5] + w1.z * xr[6] + w1.w * xr[7];
    }
}

__global__ __launch_bounds__(640)
void digitcaps_fallback(const float* __restrict__ x, const float* __restrict__ W,
                        const float* __restrict__ bias, float* __restrict__ out)
{
    __shared__ float x_lds[NI * XPAD];
    __shared__ float blog_lds[64][NO + 1];
    __shared__ float v_lds[NO][NK];
    const int b = blockIdx.x, tid = threadIdx.x;
    const int o = tid >> 6, il = tid & 63;
    const float* xb = x + (size_t)b * (NI * DI);
    for (int idx = tid; idx < NI * DI; idx += 640)
        x_lds[(idx >> 3) * XPAD + (idx & 7)] = xb[idx];
    float bias_r[NK];
#pragma unroll
    for (int k = 0; k < NK; ++k) bias_r[k] = bias[o * NK + k];
    __syncthreads();
    float blog[18], s_acc[NK];
    auto finish = [&](int it) {
#pragma unroll
        for (int off = 32; off >= 1; off >>= 1)
#pragma unroll
            for (int k = 0; k < NK; ++k) s_acc[k] += __shfl_xor(s_acc[k], off, 64);
        float sv[NK], sq = 0.f;
#pragma unroll
        for (int k = 0; k < NK; ++k) { sv[k] = s_acc[k] + bias_r[k]; sq += sv[k] * sv[k]; }
        const float scale = sq / (1.f + sq) / sqrtf(sq + 1e-9f);
        if (il == 0) {
            if (it == 2) {
#pragma unroll
                for (int k = 0; k < NK; ++k) out[(size_t)b * 160 + o * NK + k] = scale * sv[k];
            } else {
#pragma unroll
                for (int k = 0; k < NK; ++k) v_lds[o][k] = scale * sv[k];
            }
        }
    };
#pragma unroll
    for (int k = 0; k < NK; ++k) s_acc[k] = 0.f;
    for (int c = 0; c < 18; ++c) {
        float u[NK];
        compute_uhat_fb(c * 64 + il, o, x_lds, W, u);
#pragma unroll
        for (int k = 0; k < NK; ++k) s_acc[k] += u[k];
        blog[c] = 0.f;
    }
#pragma unroll
    for (int k = 0; k < NK; ++k) s_acc[k] *= 0.1f;
    finish(0);
    __syncthreads();
    for (int it = 1; it <= 2; ++it) {
#pragma unroll
        for (int k = 0; k < NK; ++k) s_acc[k] = 0.f;
        for (int c = 0; c < 18; ++c) {
            const int i = c * 64 + il;
            float u[NK];
            compute_uhat_fb(i, o, x_lds, W, u);
            float a = 0.f;
#pragma unroll
            for (int k = 0; k < NK; ++k) a += v_lds[o][k] * u[k];
            blog[c] += a;
            __syncthreads();
            blog_lds[il][o] = blog[c];
            __syncthreads();
            float m = blog_lds[il][0];
#pragma unroll
            for (int oo = 1; oo < NO; ++oo) m = fmaxf(m, blog_lds[il][oo]);
            float den = 0.f;
#pragma unroll
            for (int oo = 0; oo < NO; ++oo) den += __expf(blog_lds[il][oo] - m);
            const float cv = __expf(blog[c] - m) / den;
#pragma unroll
            for (int k = 0; k < NK; ++k) s_acc[k] += cv * u[k];
        }
        finish(it);
        __syncthreads();
    }
}

extern "C" void kernel_launch(void* const* d_in, const int* in_sizes, int n_in,
                              void* d_out, int out_size, void* d_ws, size_t ws_size,
                              hipStream_t stream)
{
    const float* x    = (const float*)d_in[0];  // [256,1152,8]
    const float* W    = (const float*)d_in[1];  // [1152,10,16,8]
    const float* bias = (const float*)d_in[2];  // [10,16]
    float* out = (float*)d_out;                 // [256,10,16]

    if (ws_size >= WS_NEED) {
        uhat_kernel<<<dim3(NC, 16), 320, 0, stream>>>(x, W, (uint32_t*)d_ws);
        route_kernel<<<NB, 1024, 0, stream>>>(bias, out, (const uint32_t*)d_ws);
    } else {
        digitcaps_fallback<<<NB, 640, 0, stream>>>(x, W, bias, out);
    }
}

// Round 5
// 145.653 us; speedup vs baseline: 3.2436x; 3.2436x over previous
//
#include <hip/hip_runtime.h>
#include <hip/hip_fp16.h>
#include <stdint.h>

#define NB 256     // batch
#define NI 1152    // input capsules
#define DI 8       // input capsule dim
#define NO 10      // output capsules
#define NK 16      // output capsule dim
#define NC 36      // i-chunks of 32
#define XPAD 10    // x_lds row stride (2-way bank aliasing = free; float2-aligned)

// ws: u_hat fp16, [b][c36][h2][o10][il32][k2q4 u32] = 23,592,960 u32 (90 MiB)
#define WS_NEED 94371840ull

// ---------------------------------------------------------------------------
// Kernel A: pure u_hat producer. grid (36, 16), 320 thr = (o10, il32).
// No reductions, no atomics — just FMA + dense coalesced fp16 stores.
// ---------------------------------------------------------------------------
__global__ __launch_bounds__(320)
void uhat_kernel(const float* __restrict__ x, const float* __restrict__ W,
                 uint32_t* __restrict__ ws)
{
    __shared__ float x_lds[16 * 32 * XPAD];   // [bb][il][d], 20 KB

    const int c   = blockIdx.x;
    const int b0  = blockIdx.y * 16;
    const int tid = threadIdx.x;
    const int o   = tid >> 5;
    const int il  = tid & 31;

    for (int idx = tid; idx < 16 * 256; idx += 320) {
        const int bb = idx >> 8, r = idx & 255;
        x_lds[bb * (32 * XPAD) + (r >> 3) * XPAD + (r & 7)] =
            x[(size_t)(b0 + bb) * (NI * DI) + c * 256 + r];
    }
    __syncthreads();

    const int i = c * 32 + il;
    const float4* wp = reinterpret_cast<const float4*>(W + ((size_t)i * NO + o) * (NK * DI));

#pragma unroll
    for (int h = 0; h < 2; ++h) {          // k = h*8 + kk
        float4 wr[16];
#pragma unroll
        for (int t = 0; t < 16; ++t) wr[t] = wp[h * 16 + t];

        for (int bb = 0; bb < 16; ++bb) {
            const float2* xp = reinterpret_cast<const float2*>(
                &x_lds[bb * (32 * XPAD) + il * XPAD]);
            const float2 x01 = xp[0], x23 = xp[1], x45 = xp[2], x67 = xp[3];

            float u[8];
#pragma unroll
            for (int kk = 0; kk < 8; ++kk) {
                const float4 w0 = wr[2 * kk], w1 = wr[2 * kk + 1];
                u[kk] = w0.x * x01.x + w0.y * x01.y + w0.z * x23.x + w0.w * x23.y +
                        w1.x * x45.x + w1.y * x45.y + w1.z * x67.x + w1.w * x67.y;
            }

            uint32_t pk[4];
#pragma unroll
            for (int t = 0; t < 4; ++t) {
                union { __half2 h2; uint32_t w; } cv;
                cv.h2 = __float22half2_rn(make_float2(u[2 * t], u[2 * t + 1]));
                pk[t] = cv.w;
            }
            // wave (2 o's x 32 il) writes two dense 512B runs
            const size_t base =
                ((((size_t)(b0 + bb) * NC + c) * 2 + h) * NO + o) * 128 + il * 4;
            *reinterpret_cast<uint4*>(ws + base) = make_uint4(pk[0], pk[1], pk[2], pk[3]);
        }
    }
}

// ---------------------------------------------------------------------------
// Kernel B: s0 prologue + 2 routing iterations. grid 256, 768 thr = 12 waves.
// lane l: ii = l>>3 (i-sub), k2 = l&7 (k-pair); wave w owns i in [w*96,(w+1)*96)
// as 12 steps of 8. k-reduce = 3 shfl_xor; softmax over o thread-local.
// ---------------------------------------------------------------------------
#define BW    12
#define BSTEP 12

__global__ __launch_bounds__(768)
void route_kernel(const float* __restrict__ bias, float* __restrict__ out,
                  const uint32_t* __restrict__ ws)
{
    __shared__ float v_lds[NO * NK];        // 640 B
    __shared__ float s_red[BW][NO * NK];    // 7.7 KB
    __shared__ float blog_lds[NI * 11];     // 50.7 KB, wave-private rows

    const int tid = threadIdx.x;
    const int b   = blockIdx.x;
    const int w   = tid >> 6;
    const int l   = tid & 63;
    const int ii  = l >> 3;
    const int k2  = l & 7;
    const int k0  = k2 * 2;
    const int h   = k2 >> 2;
    const int k2q = k2 & 3;

    const uint32_t* ub = ws + (size_t)b * 92160 + h * 1280 + k2q;
    const int ibase = w * 96;

    float s0a[NO], s1a[NO];

    // ---------------- prologue: s0 = 0.1 * sum_i u; v0 = squash(s0+bias) -----
#pragma unroll
    for (int o = 0; o < NO; ++o) { s0a[o] = 0.f; s1a[o] = 0.f; }

    for (int s = 0; s < BSTEP; ++s) {
        const int i = ibase + s * 8 + ii;
        const uint32_t* up = ub + (i >> 5) * 2560 + (i & 31) * 4;
#pragma unroll
        for (int o = 0; o < NO; ++o) {
            union { uint32_t u; __half2 h2; } cv; cv.u = up[o * 128];
            const float2 f = __half22float2(cv.h2);
            s0a[o] += f.x; s1a[o] += f.y;
        }
    }
#pragma unroll
    for (int m = 8; m <= 32; m <<= 1)
#pragma unroll
        for (int o = 0; o < NO; ++o) {
            s0a[o] += __shfl_xor(s0a[o], m, 64);
            s1a[o] += __shfl_xor(s1a[o], m, 64);
        }
    if (ii == 0) {
#pragma unroll
        for (int o = 0; o < NO; ++o) {
            s_red[w][o * NK + k0]     = s0a[o];
            s_red[w][o * NK + k0 + 1] = s1a[o];
        }
    }
    __syncthreads();
    if (tid < NO * NK) {
        float acc = 0.f;
#pragma unroll
        for (int ww = 0; ww < BW; ++ww) acc += s_red[ww][tid];
        const float sv = 0.1f * acc + bias[tid];
        float sq = sv * sv;
#pragma unroll
        for (int m = 8; m >= 1; m >>= 1) sq += __shfl_xor(sq, m, 64);
        const float scale = sq / (1.f + sq) / sqrtf(sq + 1e-9f);
        v_lds[tid] = scale * sv;
    }
    __syncthreads();

    // ---------------- iterations ----------------
    for (int it = 0; it < 2; ++it) {
        float vk0[NO], vk1[NO];
#pragma unroll
        for (int o = 0; o < NO; ++o) {
            vk0[o] = v_lds[o * NK + k0];
            vk1[o] = v_lds[o * NK + k0 + 1];
        }
#pragma unroll
        for (int o = 0; o < NO; ++o) { s0a[o] = 0.f; s1a[o] = 0.f; }

        uint32_t uu[NO];
        {
            const int i0 = ibase + ii;
            const uint32_t* up = ub + (i0 >> 5) * 2560 + (i0 & 31) * 4;
#pragma unroll
            for (int o = 0; o < NO; ++o) uu[o] = up[o * 128];
        }

        for (int s = 0; s < BSTEP; ++s) {
            const int i = ibase + s * 8 + ii;

            float fx[NO], fy[NO];
#pragma unroll
            for (int o = 0; o < NO; ++o) {
                union { uint32_t u; __half2 h2; } cv; cv.u = uu[o];
                const float2 f = __half22float2(cv.h2);
                fx[o] = f.x; fy[o] = f.y;
            }
            if (s + 1 < BSTEP) {            // prefetch next step
                const int i2 = ibase + (s + 1) * 8 + ii;
                const uint32_t* up2 = ub + (i2 >> 5) * 2560 + (i2 & 31) * 4;
#pragma unroll
                for (int o = 0; o < NO; ++o) uu[o] = up2[o * 128];
            }

            float a[NO];
#pragma unroll
            for (int o = 0; o < NO; ++o) a[o] = vk0[o] * fx[o] + vk1[o] * fy[o];
            // k-reduce over the 8 k2-lanes: all lanes end with full 16-k dot
#pragma unroll
            for (int m = 1; m <= 4; m <<= 1)
#pragma unroll
                for (int o = 0; o < NO; ++o) a[o] += __shfl_xor(a[o], m, 64);

            const int row = i * 11;
            float tot[NO];
            if (it == 0) {
#pragma unroll
                for (int o = 0; o < NO; ++o) tot[o] = a[o];
                // stash logits (wave-private rows); static-index select
                float w0v = 0.f, w1v = 0.f;
#pragma unroll
                for (int o = 0; o < 8; ++o) if (k2 == o) w0v = a[o];
#pragma unroll
                for (int o = 0; o < 2; ++o) if (k2 == o) w1v = a[8 + o];
                blog_lds[row + k2] = w0v;
                if (k2 < 2) blog_lds[row + 8 + k2] = w1v;
            } else {
#pragma unroll
                for (int o = 0; o < NO; ++o) tot[o] = blog_lds[row + o] + a[o];
            }

            // thread-local softmax over o (logits bounded ~|20| -> no max-sub)
            float e[NO], den = 0.f;
#pragma unroll
            for (int o = 0; o < NO; ++o) { e[o] = __expf(tot[o]); den += e[o]; }
            const float rden = 1.f / den;
#pragma unroll
            for (int o = 0; o < NO; ++o) {
                const float cc = e[o] * rden;
                s0a[o] += cc * fx[o];
                s1a[o] += cc * fy[o];
            }
        }

        // reduce s over ii-lanes, publish, cross-wave squash
#pragma unroll
        for (int m = 8; m <= 32; m <<= 1)
#pragma unroll
            for (int o = 0; o < NO; ++o) {
                s0a[o] += __shfl_xor(s0a[o], m, 64);
                s1a[o] += __shfl_xor(s1a[o], m, 64);
            }
        if (ii == 0) {
#pragma unroll
            for (int o = 0; o < NO; ++o) {
                s_red[w][o * NK + k0]     = s0a[o];
                s_red[w][o * NK + k0 + 1] = s1a[o];
            }
        }
        __syncthreads();

        if (tid < NO * NK) {
            float sv = bias[tid];
#pragma unroll
            for (int ww = 0; ww < BW; ++ww) sv += s_red[ww][tid];
            float sq = sv * sv;
#pragma unroll
            for (int m = 8; m >= 1; m >>= 1) sq += __shfl_xor(sq, m, 64);
            const float scale = sq / (1.f + sq) / sqrtf(sq + 1e-9f);
            if (it == 1) out[(size_t)b * (NO * NK) + tid] = scale * sv;
            else         v_lds[tid] = scale * sv;
        }
        __syncthreads();
    }
}

// ---------------------------------------------------------------------------
// Fallback (ws too small): monolithic, recompute u_hat per pass
// ---------------------------------------------------------------------------
__device__ __forceinline__ void compute_uhat_fb(int i, int o,
        const float* x_lds, const float* __restrict__ W, float* u)
{
    float xr[DI];
#pragma unroll
    for (int d = 0; d < DI; ++d) xr[d] = x_lds[i * 9 + d];
    const float4* wp = reinterpret_cast<const float4*>(W + (size_t)(i * NO + o) * (NK * DI));
#pragma unroll
    for (int k = 0; k < NK; ++k) {
        float4 w0 = wp[2 * k], w1 = wp[2 * k + 1];
        u[k] = w0.x * xr[0] + w0.y * xr[1] + w0.z * xr[2] + w0.w * xr[3] +
               w1.x * xr[4] + w1.y * xr[5] + w1.z * xr[6] + w1.w * xr[7];
    }
}

__global__ __launch_bounds__(640)
void digitcaps_fallback(const float* __restrict__ x, const float* __restrict__ W,
                        const float* __restrict__ bias, float* __restrict__ out)
{
    __shared__ float x_lds[NI * 9];
    __shared__ float blog_lds[64][NO + 1];
    __shared__ float v_lds[NO][NK];
    const int b = blockIdx.x, tid = threadIdx.x;
    const int o = tid >> 6, il = tid & 63;
    const float* xb = x + (size_t)b * (NI * DI);
    for (int idx = tid; idx < NI * DI; idx += 640)
        x_lds[(idx >> 3) * 9 + (idx & 7)] = xb[idx];
    float bias_r[NK];
#pragma unroll
    for (int k = 0; k < NK; ++k) bias_r[k] = bias[o * NK + k];
    __syncthreads();
    float blog[18], s_acc[NK];
    auto finish = [&](int it) {
#pragma unroll
        for (int off = 32; off >= 1; off >>= 1)
#pragma unroll
            for (int k = 0; k < NK; ++k) s_acc[k] += __shfl_xor(s_acc[k], off, 64);
        float sv[NK], sq = 0.f;
#pragma unroll
        for (int k = 0; k < NK; ++k) { sv[k] = s_acc[k] + bias_r[k]; sq += sv[k] * sv[k]; }
        const float scale = sq / (1.f + sq) / sqrtf(sq + 1e-9f);
        if (il == 0) {
            if (it == 2) {
#pragma unroll
                for (int k = 0; k < NK; ++k) out[(size_t)b * 160 + o * NK + k] = scale * sv[k];
            } else {
#pragma unroll
                for (int k = 0; k < NK; ++k) v_lds[o][k] = scale * sv[k];
            }
        }
    };
#pragma unroll
    for (int k = 0; k < NK; ++k) s_acc[k] = 0.f;
    for (int c = 0; c < 18; ++c) {
        float u[NK];
        compute_uhat_fb(c * 64 + il, o, x_lds, W, u);
#pragma unroll
        for (int k = 0; k < NK; ++k) s_acc[k] += u[k];
        blog[c] = 0.f;
    }
#pragma unroll
    for (int k = 0; k < NK; ++k) s_acc[k] *= 0.1f;
    finish(0);
    __syncthreads();
    for (int it = 1; it <= 2; ++it) {
#pragma unroll
        for (int k = 0; k < NK; ++k) s_acc[k] = 0.f;
        for (int c = 0; c < 18; ++c) {
            const int i = c * 64 + il;
            float u[NK];
            compute_uhat_fb(i, o, x_lds, W, u);
            float a = 0.f;
#pragma unroll
            for (int k = 0; k < NK; ++k) a += v_lds[o][k] * u[k];
            blog[c] += a;
            __syncthreads();
            blog_lds[il][o] = blog[c];
            __syncthreads();
            float m = blog_lds[il][0];
#pragma unroll
            for (int oo = 1; oo < NO; ++oo) m = fmaxf(m, blog_lds[il][oo]);
            float den = 0.f;
#pragma unroll
            for (int oo = 0; oo < NO; ++oo) den += __expf(blog_lds[il][oo] - m);
            const float cv = __expf(blog[c] - m) / den;
#pragma unroll
            for (int k = 0; k < NK; ++k) s_acc[k] += cv * u[k];
        }
        finish(it);
        __syncthreads();
    }
}

extern "C" void kernel_launch(void* const* d_in, const int* in_sizes, int n_in,
                              void* d_out, int out_size, void* d_ws, size_t ws_size,
                              hipStream_t stream)
{
    const float* x    = (const float*)d_in[0];  // [256,1152,8]
    const float* W    = (const float*)d_in[1];  // [1152,10,16,8]
    const float* bias = (const float*)d_in[2];  // [10,16]
    float* out = (float*)d_out;                 // [256,10,16]

    if (ws_size >= WS_NEED) {
        uhat_kernel<<<dim3(NC, 16), 320, 0, stream>>>(x, W, (uint32_t*)d_ws);
        route_kernel<<<NB, 768, 0, stream>>>(bias, out, (const uint32_t*)d_ws);
    } else {
        digitcaps_fallback<<<NB, 640, 0, stream>>>(x, W, bias, out);
    }
}